// Round 8
// baseline (627.541 us; speedup 1.0000x reference)
//
#include <hip/hip_runtime.h>
#include <hip/hip_bf16.h>
#include <stdint.h>

// ---------------------------------------------------------------------------
// DecoderLayer fused pipeline, round 7 (resubmit — GPU timeout).
// Changes vs r6 (flash only; GEMM/LN/prep identical):
//  - conflict-free P tile: in-chunk half XORed by (q>>3); writer 4x b64,
//    reader 4x b64 (was 2x b128) -> SQ_LDS_BANK_CONFLICT 2.1M -> ~0
//  - T13 defer-max: skip O-rescale/bpermutes when max growth <= 8 exp2-units
//  - XCD-aware block swizzle: all 32 q-tiles of a bh on one XCD (K/V L2-resident)
// ---------------------------------------------------------------------------

#define DEV static __device__ __forceinline__

typedef short bf16s;                                        // bf16 storage
typedef __attribute__((ext_vector_type(8))) short bf16x8;   // MFMA A/B frag
typedef __attribute__((ext_vector_type(4))) float f32x4;    // MFMA C/D frag

DEV short f2b(float f) {
    union { __hip_bfloat16 h; short s; } u;
    u.h = __float2bfloat16(f);
    return u.s;
}

DEV unsigned pk2(float lo, float hi) {
    union { __hip_bfloat162 h; unsigned u; } u;
    u.h = __float22bfloat162_rn(float2{lo, hi});
    return u.u;
}

DEV f32x4 mfma16(bf16x8 a, bf16x8 b, f32x4 c) {
    return __builtin_amdgcn_mfma_f32_16x16x32_bf16(a, b, c, 0, 0, 0);
}

DEV void gload_lds16(const bf16s* g, short* l) {
    __builtin_amdgcn_global_load_lds(
        (const __attribute__((address_space(1))) void*)g,
        (__attribute__((address_space(3))) void*)l,
        16, 0, 0);
}

// ---------------------------------------------------------------------------
// cast fp32 -> bf16 for x and enc in one launch (outputs contiguous)
// ---------------------------------------------------------------------------
__global__ __launch_bounds__(256) void cast2_f32_bf16_kernel(
    const float* __restrict__ a, const float* __restrict__ b,
    bf16s* __restrict__ out, int n)
{
    int i = (blockIdx.x * 256 + threadIdx.x) * 8;
    const float* src = (i < n) ? a : b;
    int j = (i < n) ? i : i - n;
    const float4 u = *(const float4*)(src + j);
    const float4 v = *(const float4*)(src + j + 4);
    bf16x8 r;
    r[0] = f2b(u.x); r[1] = f2b(u.y); r[2] = f2b(u.z); r[3] = f2b(u.w);
    r[4] = f2b(v.x); r[5] = f2b(v.y); r[6] = f2b(v.z); r[7] = f2b(v.w);
    *(bf16x8*)(out + i) = r;
}

// ---------------------------------------------------------------------------
// 8x (1024x1024) W fp32 [K][N] -> Wt bf16 [N][K], one launch, z = slot
// ---------------------------------------------------------------------------
struct P8 { const float* p[8]; };

__global__ __launch_bounds__(256) void transpose_cast8_kernel(
    P8 srcs, bf16s* __restrict__ dst)
{
    __shared__ short tile[64][65];
    const float* W = srcs.p[blockIdx.z];
    bf16s* Wt = dst + (size_t)blockIdx.z * 1024 * 1024;
    const int n0 = blockIdx.x * 64, k0 = blockIdx.y * 64;
    const int t = threadIdx.x;
#pragma unroll
    for (int it = 0; it < 16; ++it) {
        int idx = it * 256 + t;
        int r = idx >> 6, c = idx & 63;
        tile[r][c] = f2b(W[(size_t)(k0 + r) * 1024 + n0 + c]);
    }
    __syncthreads();
#pragma unroll
    for (int it = 0; it < 16; ++it) {
        int idx = it * 256 + t;
        int r = idx >> 6, c = idx & 63;
        Wt[(size_t)(n0 + r) * 1024 + k0 + c] = tile[c][r];
    }
}

// generic single transpose (FFN weights)
__global__ __launch_bounds__(256) void transpose_cast_kernel(
    const float* __restrict__ W, bf16s* __restrict__ Wt, int Krows, int Ncols)
{
    __shared__ short tile[64][65];
    const int n0 = blockIdx.x * 64, k0 = blockIdx.y * 64;
    const int t = threadIdx.x;
#pragma unroll
    for (int it = 0; it < 16; ++it) {
        int idx = it * 256 + t;
        int r = idx >> 6, c = idx & 63;
        tile[r][c] = f2b(W[(size_t)(k0 + r) * Ncols + n0 + c]);
    }
    __syncthreads();
#pragma unroll
    for (int it = 0; it < 16; ++it) {
        int idx = it * 256 + t;
        int r = idx >> 6, c = idx & 63;
        Wt[(size_t)(n0 + r) * Krows + k0 + c] = tile[c][r];
    }
}

// ---------------------------------------------------------------------------
// V bf16 [rows][ldv] (col-offset pre-added) -> Vt bf16 [B*NH][64][Sk]
// ---------------------------------------------------------------------------
__global__ __launch_bounds__(256) void transpose_v_kernel(
    const bf16s* __restrict__ V, int ldv, bf16s* __restrict__ Vt, int Sk)
{
    __shared__ short tile[64][65];
    const int s0 = blockIdx.x * 64;
    const int bh = blockIdx.y, b = bh >> 4, h = bh & 15;
    const int t = threadIdx.x;
#pragma unroll
    for (int it = 0; it < 16; ++it) {
        int idx = it * 256 + t;
        int r = idx >> 6, c = idx & 63;
        tile[r][c] = V[(size_t)(b * Sk + s0 + r) * ldv + h * 64 + c];
    }
    __syncthreads();
#pragma unroll
    for (int it = 0; it < 16; ++it) {
        int idx = it * 256 + t;
        int r = idx >> 6, c = idx & 63;
        Vt[((size_t)bh * 64 + r) * Sk + s0 + c] = tile[c][r];
    }
}

// ---------------------------------------------------------------------------
// bias concat helpers
// ---------------------------------------------------------------------------
__global__ void concat3_kernel(const float* a, const float* b, const float* c,
                               float* o, int n)
{
    int i = blockIdx.x * 256 + threadIdx.x;
    if (i < n) { o[i] = a[i]; o[n + i] = b[i]; o[2 * n + i] = c[i]; }
}
__global__ void concat2_kernel(const float* a, const float* b, float* o, int n)
{
    int i = blockIdx.x * 256 + threadIdx.x;
    if (i < n) { o[i] = a[i]; o[n + i] = b[i]; }
}

// ---------------------------------------------------------------------------
// GEMM: C[M][N] = A[M][K](bf16) @ Bt[N][K](bf16)^T + bias, opt ReLU.
// (unchanged from r2: 2-phase prefetch, double-buffered LDS, 1 barrier/step)
// ---------------------------------------------------------------------------
template<int BM, int OUT_BF16, int RELU>
__global__ __launch_bounds__(256, (BM == 64 ? 4 : 2))
void gemm_bt_kernel(const bf16s* __restrict__ A, const bf16s* __restrict__ Bt,
                    const float* __restrict__ bias, void* __restrict__ Cp,
                    int M, int N, int K)
{
    constexpr int BN = 128;
    constexpr int WR = BM / 64;
    constexpr int WC = 4 / WR;
    constexpr int TN = BN / WC;
    constexpr int NF = TN / 16;
    constexpr int RA = BM / 64;
    constexpr int ASZ = BM * 32;

    __shared__ short As[2 * ASZ];
    __shared__ short Bs[2 * BN * 32];

    const int t = threadIdx.x, lane = t & 63, wave = t >> 6;
    const int g = lane >> 4, ln16 = lane & 15;
    const int wr = wave / WC, wc = wave % WC;
    const int rowA0 = blockIdx.y * BM, rowB0 = blockIdx.x * BN;

    const bf16s* Ab = A + (size_t)rowA0 * K;
    const bf16s* Bb = Bt + (size_t)rowB0 * K;

    f32x4 acc[4][NF] = {};

    auto stage = [&](int buf, int k0) {
        short* Ad = As + buf * ASZ;
        short* Bd = Bs + buf * BN * 32;
#pragma unroll
        for (int rnd = 0; rnd < RA; ++rnd) {
            int p = rnd * 256 + t;
            int sr = p >> 3, c3 = (p & 7) ^ (sr & 7);
            int r = sr * 2 + (c3 >> 2), c = c3 & 3;
            gload_lds16(Ab + (size_t)r * K + k0 + c * 8,
                        Ad + (rnd * 256 + wave * 64) * 8);
        }
#pragma unroll
        for (int rnd = 0; rnd < 2; ++rnd) {
            int p = rnd * 256 + t;
            int sr = p >> 3, c3 = (p & 7) ^ (sr & 7);
            int r = sr * 2 + (c3 >> 2), c = c3 & 3;
            gload_lds16(Bb + (size_t)r * K + k0 + c * 8,
                        Bd + (rnd * 256 + wave * 64) * 8);
        }
    };

    stage(0, 0);
    __syncthreads();
    int cur = 0;
    for (int k0 = 0; k0 < K; k0 += 32) {
        if (k0 + 32 < K) stage(cur ^ 1, k0 + 32);
        const short* Ar = As + cur * ASZ;
        const short* Br = Bs + cur * BN * 32;
        bf16x8 af[4], bfr[NF];
#pragma unroll
        for (int m = 0; m < 4; ++m) {
            int r = wr * 64 + m * 16 + ln16;
            int sr = r >> 1, c3 = (r & 1) * 4 + g;
            af[m] = *(const bf16x8*)(Ar + sr * 64 + ((c3 ^ (sr & 7)) * 8));
        }
#pragma unroll
        for (int n = 0; n < NF; ++n) {
            int r = wc * TN + n * 16 + ln16;
            int sr = r >> 1, c3 = (r & 1) * 4 + g;
            bfr[n] = *(const bf16x8*)(Br + sr * 64 + ((c3 ^ (sr & 7)) * 8));
        }
#pragma unroll
        for (int m = 0; m < 4; ++m)
#pragma unroll
            for (int n = 0; n < NF; ++n)
                acc[m][n] = mfma16(af[m], bfr[n], acc[m][n]);
        __syncthreads();
        cur ^= 1;
    }

    const int row0 = rowA0 + wr * 64, col0 = rowB0 + wc * TN;
#pragma unroll
    for (int n = 0; n < NF; ++n) {
        const int col = col0 + n * 16 + ln16;
        const float bv = bias[col];
#pragma unroll
        for (int m = 0; m < 4; ++m) {
#pragma unroll
            for (int r = 0; r < 4; ++r) {
                int row = row0 + m * 16 + g * 4 + r;
                float v = acc[m][n][r] + bv;
                if (RELU) v = fmaxf(v, 0.f);
                if (OUT_BF16) ((bf16s*)Cp)[(size_t)row * N + col] = f2b(v);
                else          ((float*)Cp)[(size_t)row * N + col] = v;
            }
        }
    }
}

// ---------------------------------------------------------------------------
// Flash attention, transposed-softmax + conflict-free P + defer-max + XCD swz.
// 1D grid: id&7 = XCD slot, 4 bh-columns per XCD -> K/V stays L2-resident.
// P tile layout: chunk = c ^ (q&7); in-chunk half = half ^ (q>>3); both the
// 16-lane write group and read group then cover all 32 banks.
// ---------------------------------------------------------------------------
template<int CAUSAL>
__global__ __launch_bounds__(256, 4)
void flash_kernel(const bf16s* __restrict__ Q, int ldq,
                  const bf16s* __restrict__ K, int ldk,
                  const bf16s* __restrict__ Vt,
                  bf16s* __restrict__ O, int ldo,
                  int Sq, int Sk, float scale)
{
    __shared__ short Ks[2 * 64 * 64];
    __shared__ short Vs[2 * 64 * 64];
    __shared__ short Ps[4 * 16 * 64];
    const int t = threadIdx.x, lane = t & 63, wave = t >> 6;
    const int g = lane >> 4, ln16 = lane & 15;

    // XCD-aware decode: id = (bh-major within XCD) * 8 + xcd
    const int nqt = Sq >> 6;                       // 32
    const int id = blockIdx.x;
    const int perx = gridDim.x >> 3;               // blocks per XCD slot
    const int bhPerX = perx / nqt;                 // bh columns per XCD
    const int idx = id >> 3;
    const int bh = (id & 7) * bhPerX + idx / nqt;
    int qt = idx % nqt;
    if (CAUSAL) qt = nqt - 1 - qt;                 // heavy q-tiles first
    const int b = bh >> 4, h = bh & 15;
    const int q0 = qt * 64;
    const float sc2 = scale * 1.44269504f;         // exp2-domain scale
    const float thrRaw = 8.0f / sc2;               // defer-max threshold (raw)

    bf16x8 aq[2];
    {
        const size_t qrow = (size_t)(b * Sq + q0 + wave * 16 + ln16);
#pragma unroll
        for (int kk = 0; kk < 2; ++kk)
            aq[kk] = *(const bf16x8*)(Q + qrow * ldq + h * 64 + kk * 32 + g * 8);
    }

    float m_raw = -1e30f, l_sum = 0.f;   // stats for q = ln16 (this wave)
    f32x4 oa[4] = {};

    const int nkt = CAUSAL ? (qt + 1) : (Sk >> 6);
    const bf16s* Kbase = K + (size_t)b * Sk * ldk + h * 64;
    const bf16s* Vbase = Vt + (size_t)bh * 64 * Sk;
    short* myP = Ps + wave * 1024;

    auto stage = [&](int buf, int kt) {
        const bf16s* ksrc = Kbase + (size_t)(kt * 64) * ldk;
        const bf16s* vsrc = Vbase + kt * 64;
        short* Kd = Ks + buf * 4096;
        short* Vd = Vs + buf * 4096;
#pragma unroll
        for (int rnd = 0; rnd < 2; ++rnd) {
            int p = rnd * 256 + t;
            int r = p >> 3, c = (p & 7) ^ (r & 7);
            gload_lds16(ksrc + (size_t)r * ldk + c * 8,
                        Kd + (rnd * 256 + wave * 64) * 8);
        }
#pragma unroll
        for (int rnd = 0; rnd < 2; ++rnd) {
            int p = rnd * 256 + t;
            int r = p >> 3, c = (p & 7) ^ (r & 7);
            gload_lds16(vsrc + (size_t)r * Sk + c * 8,
                        Vd + (rnd * 256 + wave * 64) * 8);
        }
    };

    stage(0, 0);
    __syncthreads();
    int cur = 0;

    for (int kt = 0; kt < nkt; ++kt) {
        if (kt + 1 < nkt) stage(cur ^ 1, kt + 1);
        const short* Kr = Ks + cur * 4096;
        const short* Vr = Vs + cur * 4096;

        // ---- S^T = K Q^T: lane holds q=ln16, keys n*16+g*4+r (raw) ----
        f32x4 sa[4] = {};
        __builtin_amdgcn_s_setprio(1);
#pragma unroll
        for (int kk = 0; kk < 2; ++kk) {
#pragma unroll
            for (int n = 0; n < 4; ++n) {
                int key = n * 16 + ln16;
                bf16x8 ak = *(const bf16x8*)(Kr + key * 64 +
                                             (((kk * 4 + g) ^ (key & 7)) * 8));
                sa[n] = mfma16(ak, aq[kk], sa[n]);
            }
        }
        __builtin_amdgcn_s_setprio(0);

        float sv[4][4];
        const bool diag = CAUSAL && (kt == qt);
#pragma unroll
        for (int n = 0; n < 4; ++n)
#pragma unroll
            for (int r = 0; r < 4; ++r) {
                float s = sa[n][r];
                if (diag && (n * 16 + g * 4 + r > wave * 16 + ln16)) s = -1e30f;
                sv[n][r] = s;
            }

        // ---- row max: in-lane tree + cross-g (2 shuffles) ----
        float rm = fmaxf(
            fmaxf(fmaxf(fmaxf(sv[0][0], sv[0][1]), fmaxf(sv[0][2], sv[0][3])),
                  fmaxf(fmaxf(sv[1][0], sv[1][1]), fmaxf(sv[1][2], sv[1][3]))),
            fmaxf(fmaxf(fmaxf(sv[2][0], sv[2][1]), fmaxf(sv[2][2], sv[2][3])),
                  fmaxf(fmaxf(sv[3][0], sv[3][1]), fmaxf(sv[3][2], sv[3][3]))));
        rm = fmaxf(rm, __shfl_xor(rm, 16, 64));
        rm = fmaxf(rm, __shfl_xor(rm, 32, 64));

        // ---- defer-max (T13): only rescale when max grew past headroom ----
        if (!__all(rm <= m_raw + thrRaw)) {
            const float mnew = fmaxf(m_raw, rm);
            const float al = exp2f((m_raw - mnew) * sc2);
            m_raw = mnew;
            l_sum *= al;
            float alr[4];
#pragma unroll
            for (int r = 0; r < 4; ++r)
                alr[r] = __shfl(al, g * 4 + r, 64);
#pragma unroll
            for (int n = 0; n < 4; ++n)
#pragma unroll
                for (int r = 0; r < 4; ++r)
                    oa[n][r] *= alr[r];
        }
        const float nm = -m_raw * sc2;

        float rs = 0.f;
#pragma unroll
        for (int n = 0; n < 4; ++n)
#pragma unroll
            for (int r = 0; r < 4; ++r) {
                float p = exp2f(fmaf(sv[n][r], sc2, nm));
                sv[n][r] = p;
                rs += p;
            }
        rs += __shfl_xor(rs, 16, 64);
        rs += __shfl_xor(rs, 32, 64);
        l_sum += rs;

        // ---- P -> LDS: 4x b64, chunk ^ (q&7), half ^ (q>>3): bank-clean ----
#pragma unroll
        for (int n = 0; n < 4; ++n) {
            uint2 w;
            w.x = pk2(sv[n][0], sv[n][1]);
            w.y = pk2(sv[n][2], sv[n][3]);
            int c = n * 2 + (g >> 1);
            int sh = ln16 * 64 + ((c ^ (ln16 & 7)) * 8) +
                     (((g & 1) ^ (ln16 >> 3)) * 4);
            *(uint2*)(myP + sh) = w;
        }
        asm volatile("s_waitcnt lgkmcnt(0)" ::: "memory");

        // ---- O += P @ V ----
        __builtin_amdgcn_s_setprio(1);
#pragma unroll
        for (int kk = 0; kk < 2; ++kk) {
            const int base = ln16 * 64 + (((kk * 4 + g) ^ (ln16 & 7)) * 8);
            const int x0 = (ln16 >> 3) * 4;
            union { bf16x8 v; uint2 u2[2]; } pu;
            pu.u2[0] = *(const uint2*)(myP + base + x0);        // logical half 0
            pu.u2[1] = *(const uint2*)(myP + base + (x0 ^ 4));  // logical half 1
            bf16x8 pa = pu.v;
#pragma unroll
            for (int n = 0; n < 4; ++n) {
                int d = n * 16 + ln16;
                bf16x8 vb = *(const bf16x8*)(Vr + d * 64 +
                                             (((kk * 4 + g) ^ (d & 7)) * 8));
                oa[n] = mfma16(pa, vb, oa[n]);
            }
        }
        __builtin_amdgcn_s_setprio(0);
        __syncthreads();
        cur ^= 1;
    }

    const float inv = 1.f / l_sum;
    float invr[4];
#pragma unroll
    for (int r = 0; r < 4; ++r)
        invr[r] = __shfl(inv, g * 4 + r, 64);
#pragma unroll
    for (int n = 0; n < 4; ++n)
#pragma unroll
        for (int r = 0; r < 4; ++r) {
            int q = q0 + wave * 16 + g * 4 + r;
            int d = h * 64 + n * 16 + ln16;
            O[(size_t)(b * Sq + q) * ldo + d] = f2b(oa[n][r] * invr[r]);
        }
}

// ---------------------------------------------------------------------------
// y = LN(x + a) * g + b   (D=1024, one block/row, fp32), opt bf16 copy out
// ---------------------------------------------------------------------------
template<int WRITE_BF16>
__global__ __launch_bounds__(256)
void add_ln_kernel(const float* __restrict__ X, const float* __restrict__ A,
                   const float* __restrict__ G, const float* __restrict__ Bb,
                   float* __restrict__ Y, bf16s* __restrict__ Yb)
{
    const int row = blockIdx.x, t = threadIdx.x;
    const int lane = t & 63, w = t >> 6;
    const size_t base = (size_t)row * 1024 + t * 4;
    const float4 xv = *(const float4*)(X + base);
    const float4 av = *(const float4*)(A + base);
    float4 v;
    v.x = xv.x + av.x; v.y = xv.y + av.y; v.z = xv.z + av.z; v.w = xv.w + av.w;
    float s = v.x + v.y + v.z + v.w;
    float q = v.x * v.x + v.y * v.y + v.z * v.z + v.w * v.w;
#pragma unroll
    for (int x = 1; x < 64; x <<= 1) {
        s += __shfl_xor(s, x, 64);
        q += __shfl_xor(q, x, 64);
    }
    __shared__ float red[8];
    if (lane == 0) { red[w] = s; red[4 + w] = q; }
    __syncthreads();
    s = red[0] + red[1] + red[2] + red[3];
    q = red[4] + red[5] + red[6] + red[7];
    const float mu = s * (1.f / 1024.f);
    const float var = q * (1.f / 1024.f) - mu * mu;
    const float rstd = rsqrtf(var + 1e-5f);
    const float4 gv = *(const float4*)(G + t * 4);
    const float4 bv = *(const float4*)(Bb + t * 4);
    float o0 = (v.x - mu) * rstd * gv.x + bv.x;
    float o1 = (v.y - mu) * rstd * gv.y + bv.y;
    float o2 = (v.z - mu) * rstd * gv.z + bv.z;
    float o3 = (v.w - mu) * rstd * gv.w + bv.w;
    float4 ov; ov.x = o0; ov.y = o1; ov.z = o2; ov.w = o3;
    *(float4*)(Y + base) = ov;
    if (WRITE_BF16) {
        short4 yb;
        yb.x = f2b(o0); yb.y = f2b(o1); yb.z = f2b(o2); yb.w = f2b(o3);
        *(short4*)(Yb + base) = yb;
    }
}

// ---------------------------------------------------------------------------
// launch
// ---------------------------------------------------------------------------
extern "C" void kernel_launch(void* const* d_in, const int* in_sizes, int n_in,
                              void* d_out, int out_size, void* d_ws, size_t ws_size,
                              hipStream_t stream)
{
    constexpr int Dm = 1024, DFF = 4096, Bq = 2, S = 2048;
    constexpr int NT = Bq * S;   // 4096 tokens
    constexpr size_t MM = (size_t)Dm * Dm;

    const float* x    = (const float*)d_in[0];
    const float* enc  = (const float*)d_in[1];
    const float* s_wq = (const float*)d_in[4];  const float* s_bq = (const float*)d_in[5];
    const float* s_wk = (const float*)d_in[6];  const float* s_bk = (const float*)d_in[7];
    const float* s_wv = (const float*)d_in[8];  const float* s_bv = (const float*)d_in[9];
    const float* s_wo = (const float*)d_in[10]; const float* s_bo = (const float*)d_in[11];
    const float* c_wq = (const float*)d_in[12]; const float* c_bq = (const float*)d_in[13];
    const float* c_wk = (const float*)d_in[14]; const float* c_bk = (const float*)d_in[15];
    const float* c_wv = (const float*)d_in[16]; const float* c_bv = (const float*)d_in[17];
    const float* c_wo = (const float*)d_in[18]; const float* c_bo = (const float*)d_in[19];
    const float* ffw1 = (const float*)d_in[20]; const float* ffb1 = (const float*)d_in[21];
    const float* ffw2 = (const float*)d_in[22]; const float* ffb2 = (const float*)d_in[23];
    const float* ln1g = (const float*)d_in[24]; const float* ln1b = (const float*)d_in[25];
    const float* ln2g = (const float*)d_in[26]; const float* ln2b = (const float*)d_in[27];
    const float* ln3g = (const float*)d_in[28]; const float* ln3b = (const float*)d_in[29];

    char* ws = (char*)d_ws;
    size_t off = 0;
    auto alloc = [&](size_t bytes) -> char* {
        char* p = ws + off;
        off += (bytes + 255) & ~(size_t)255;
        return p;
    };

    bf16s* xbf   = (bf16s*)alloc((size_t)NT * Dm * 2);
    bf16s* encbf = (bf16s*)alloc((size_t)NT * Dm * 2);   // contiguous with xbf
    bf16s* wAll  = (bf16s*)alloc(8 * MM * 2);            // 8 transposed 1024^2 weights
    bf16s* w1T   = (bf16s*)alloc((size_t)Dm * DFF * 2);
    bf16s* w2T   = (bf16s*)alloc((size_t)Dm * DFF * 2);
    float* bqkv  = (float*)alloc((size_t)3 * Dm * 4);
    float* bkvc  = (float*)alloc((size_t)2 * Dm * 4);
    bf16s* QKV   = (bf16s*)alloc((size_t)NT * 3 * Dm * 2);  // reused: Q2 + KV2
    bf16s* Vt    = (bf16s*)alloc((size_t)NT * Dm * 2);      // reused: V2t
    bf16s* AO    = (bf16s*)alloc((size_t)NT * Dm * 2);      // reused: AO2
    float* Pbuf  = (float*)alloc((size_t)NT * Dm * 4);      // reused: P1/P2/F
    float* x1f   = (float*)alloc((size_t)NT * Dm * 4);
    bf16s* x1bf  = (bf16s*)alloc((size_t)NT * Dm * 2);
    float* x2f   = (float*)alloc((size_t)NT * Dm * 4);
    bf16s* x2bf  = (bf16s*)alloc((size_t)NT * Dm * 2);
    bf16s* Hbuf  = (bf16s*)alloc((size_t)NT * DFF * 2);
    (void)ws_size; (void)in_sizes; (void)n_in; (void)out_size;

    bf16s* wqkvT = wAll;            // slots 0,1,2: s_wq, s_wk, s_wv
    bf16s* woTs  = wAll + 3 * MM;   // slot 3
    bf16s* wqTc  = wAll + 4 * MM;   // slot 4
    bf16s* wkvTc = wAll + 5 * MM;   // slots 5,6: c_wk, c_wv
    bf16s* woTc  = wAll + 7 * MM;   // slot 7

    // ---- phase 0: casts / transposes / bias concat ----
    cast2_f32_bf16_kernel<<<2 * NT * Dm / 8 / 256, 256, 0, stream>>>(
        x, enc, xbf, NT * Dm);
    P8 srcs = {{s_wq, s_wk, s_wv, s_wo, c_wq, c_wk, c_wv, c_wo}};
    transpose_cast8_kernel<<<dim3(16, 16, 8), 256, 0, stream>>>(srcs, wAll);
    transpose_cast_kernel<<<dim3(64, 16), 256, 0, stream>>>(ffw1, w1T, Dm, DFF);
    transpose_cast_kernel<<<dim3(16, 64), 256, 0, stream>>>(ffw2, w2T, DFF, Dm);
    concat3_kernel<<<4, 256, 0, stream>>>(s_bq, s_bk, s_bv, bqkv, Dm);
    concat2_kernel<<<4, 256, 0, stream>>>(c_bk, c_bv, bkvc, Dm);

    // ---- phase 1: self-attention ----
    gemm_bt_kernel<128, 1, 0><<<dim3(24, 32), 256, 0, stream>>>(
        xbf, wqkvT, bqkv, QKV, NT, 3 * Dm, Dm);
    transpose_v_kernel<<<dim3(32, 32), 256, 0, stream>>>(
        QKV + 2 * Dm, 3 * Dm, Vt, S);
    flash_kernel<1><<<dim3(1024), 256, 0, stream>>>(
        QKV, 3 * Dm, QKV + Dm, 3 * Dm, Vt, AO, Dm, S, S, 0.125f);
    gemm_bt_kernel<64, 0, 0><<<dim3(8, 64), 256, 0, stream>>>(
        AO, woTs, s_bo, Pbuf, NT, Dm, Dm);
    add_ln_kernel<1><<<NT, 256, 0, stream>>>(x, Pbuf, ln1g, ln1b, x1f, x1bf);

    // ---- phase 2: cross-attention ----
    bf16s* Q2  = QKV;
    bf16s* KV2 = QKV + (size_t)NT * Dm;
    gemm_bt_kernel<64, 1, 0><<<dim3(8, 64), 256, 0, stream>>>(
        x1bf, wqTc, c_bq, Q2, NT, Dm, Dm);
    gemm_bt_kernel<128, 1, 0><<<dim3(16, 32), 256, 0, stream>>>(
        encbf, wkvTc, bkvc, KV2, NT, 2 * Dm, Dm);
    transpose_v_kernel<<<dim3(32, 32), 256, 0, stream>>>(
        KV2 + Dm, 2 * Dm, Vt, S);
    flash_kernel<0><<<dim3(1024), 256, 0, stream>>>(
        Q2, Dm, KV2, 2 * Dm, Vt, AO, Dm, S, S, 0.125f);
    gemm_bt_kernel<64, 0, 0><<<dim3(8, 64), 256, 0, stream>>>(
        AO, woTc, c_bo, Pbuf, NT, Dm, Dm);
    add_ln_kernel<1><<<NT, 256, 0, stream>>>(x1f, Pbuf, ln2g, ln2b, x2f, x2bf);

    // ---- phase 3: FFN ----
    gemm_bt_kernel<128, 1, 1><<<dim3(32, 32), 256, 0, stream>>>(
        x2bf, w1T, ffb1, Hbuf, NT, DFF, Dm);
    gemm_bt_kernel<64, 0, 0><<<dim3(8, 64), 256, 0, stream>>>(
        Hbuf, w2T, ffb2, Pbuf, NT, Dm, DFF);
    add_ln_kernel<0><<<NT, 256, 0, stream>>>(
        x2f, Pbuf, ln3g, ln3b, (float*)d_out, nullptr);
}

// Round 10
// 606.841 us; speedup vs baseline: 1.0341x; 1.0341x over previous
//
#include <hip/hip_runtime.h>
#include <hip/hip_bf16.h>
#include <stdint.h>

// ---------------------------------------------------------------------------
// DecoderLayer fused pipeline, round 8 (resubmit — GPU timeout).
// Changes vs r7 (GEMM only; flash/LN/prep identical = measured control):
//  - BK=64 for BM=128 GEMMs (QKV, KV2, FFN1): one staged buffer holds two
//    32-deep subtiles -> 32 MFMA per barrier instead of 16; halves the
//    vmcnt-drain + barrier count. LDS 64KB/block keeps 2 blocks/CU.
//  - BM=64 GEMMs keep BK=32 (BK=64 would cost a block of occupancy).
// ---------------------------------------------------------------------------

#define DEV static __device__ __forceinline__

typedef short bf16s;                                        // bf16 storage
typedef __attribute__((ext_vector_type(8))) short bf16x8;   // MFMA A/B frag
typedef __attribute__((ext_vector_type(4))) float f32x4;    // MFMA C/D frag

DEV short f2b(float f) {
    union { __hip_bfloat16 h; short s; } u;
    u.h = __float2bfloat16(f);
    return u.s;
}

DEV unsigned pk2(float lo, float hi) {
    union { __hip_bfloat162 h; unsigned u; } u;
    u.h = __float22bfloat162_rn(float2{lo, hi});
    return u.u;
}

DEV f32x4 mfma16(bf16x8 a, bf16x8 b, f32x4 c) {
    return __builtin_amdgcn_mfma_f32_16x16x32_bf16(a, b, c, 0, 0, 0);
}

DEV void gload_lds16(const bf16s* g, short* l) {
    __builtin_amdgcn_global_load_lds(
        (const __attribute__((address_space(1))) void*)g,
        (__attribute__((address_space(3))) void*)l,
        16, 0, 0);
}

// ---------------------------------------------------------------------------
// cast fp32 -> bf16 for x and enc in one launch (outputs contiguous)
// ---------------------------------------------------------------------------
__global__ __launch_bounds__(256) void cast2_f32_bf16_kernel(
    const float* __restrict__ a, const float* __restrict__ b,
    bf16s* __restrict__ out, int n)
{
    int i = (blockIdx.x * 256 + threadIdx.x) * 8;
    const float* src = (i < n) ? a : b;
    int j = (i < n) ? i : i - n;
    const float4 u = *(const float4*)(src + j);
    const float4 v = *(const float4*)(src + j + 4);
    bf16x8 r;
    r[0] = f2b(u.x); r[1] = f2b(u.y); r[2] = f2b(u.z); r[3] = f2b(u.w);
    r[4] = f2b(v.x); r[5] = f2b(v.y); r[6] = f2b(v.z); r[7] = f2b(v.w);
    *(bf16x8*)(out + i) = r;
}

// ---------------------------------------------------------------------------
// 8x (1024x1024) W fp32 [K][N] -> Wt bf16 [N][K], one launch, z = slot
// ---------------------------------------------------------------------------
struct P8 { const float* p[8]; };

__global__ __launch_bounds__(256) void transpose_cast8_kernel(
    P8 srcs, bf16s* __restrict__ dst)
{
    __shared__ short tile[64][65];
    const float* W = srcs.p[blockIdx.z];
    bf16s* Wt = dst + (size_t)blockIdx.z * 1024 * 1024;
    const int n0 = blockIdx.x * 64, k0 = blockIdx.y * 64;
    const int t = threadIdx.x;
#pragma unroll
    for (int it = 0; it < 16; ++it) {
        int idx = it * 256 + t;
        int r = idx >> 6, c = idx & 63;
        tile[r][c] = f2b(W[(size_t)(k0 + r) * 1024 + n0 + c]);
    }
    __syncthreads();
#pragma unroll
    for (int it = 0; it < 16; ++it) {
        int idx = it * 256 + t;
        int r = idx >> 6, c = idx & 63;
        Wt[(size_t)(n0 + r) * 1024 + k0 + c] = tile[c][r];
    }
}

// generic single transpose (FFN weights)
__global__ __launch_bounds__(256) void transpose_cast_kernel(
    const float* __restrict__ W, bf16s* __restrict__ Wt, int Krows, int Ncols)
{
    __shared__ short tile[64][65];
    const int n0 = blockIdx.x * 64, k0 = blockIdx.y * 64;
    const int t = threadIdx.x;
#pragma unroll
    for (int it = 0; it < 16; ++it) {
        int idx = it * 256 + t;
        int r = idx >> 6, c = idx & 63;
        tile[r][c] = f2b(W[(size_t)(k0 + r) * Ncols + n0 + c]);
    }
    __syncthreads();
#pragma unroll
    for (int it = 0; it < 16; ++it) {
        int idx = it * 256 + t;
        int r = idx >> 6, c = idx & 63;
        Wt[(size_t)(n0 + r) * Krows + k0 + c] = tile[c][r];
    }
}

// ---------------------------------------------------------------------------
// V bf16 [rows][ldv] (col-offset pre-added) -> Vt bf16 [B*NH][64][Sk]
// ---------------------------------------------------------------------------
__global__ __launch_bounds__(256) void transpose_v_kernel(
    const bf16s* __restrict__ V, int ldv, bf16s* __restrict__ Vt, int Sk)
{
    __shared__ short tile[64][65];
    const int s0 = blockIdx.x * 64;
    const int bh = blockIdx.y, b = bh >> 4, h = bh & 15;
    const int t = threadIdx.x;
#pragma unroll
    for (int it = 0; it < 16; ++it) {
        int idx = it * 256 + t;
        int r = idx >> 6, c = idx & 63;
        tile[r][c] = V[(size_t)(b * Sk + s0 + r) * ldv + h * 64 + c];
    }
    __syncthreads();
#pragma unroll
    for (int it = 0; it < 16; ++it) {
        int idx = it * 256 + t;
        int r = idx >> 6, c = idx & 63;
        Vt[((size_t)bh * 64 + r) * Sk + s0 + c] = tile[c][r];
    }
}

// ---------------------------------------------------------------------------
// bias concat helpers
// ---------------------------------------------------------------------------
__global__ void concat3_kernel(const float* a, const float* b, const float* c,
                               float* o, int n)
{
    int i = blockIdx.x * 256 + threadIdx.x;
    if (i < n) { o[i] = a[i]; o[n + i] = b[i]; o[2 * n + i] = c[i]; }
}
__global__ void concat2_kernel(const float* a, const float* b, float* o, int n)
{
    int i = blockIdx.x * 256 + threadIdx.x;
    if (i < n) { o[i] = a[i]; o[n + i] = b[i]; }
}

// ---------------------------------------------------------------------------
// GEMM: C[M][N] = A[M][K](bf16) @ Bt[N][K](bf16)^T + bias, opt ReLU.
// 2-phase prefetch, double-buffered LDS. BK subtiles of 32: NSUB MFMA passes
// per barrier (BK=64 halves barrier count for BM=128 tiles).
// ---------------------------------------------------------------------------
template<int BM, int BK, int OUT_BF16, int RELU>
__global__ __launch_bounds__(256, (BM == 64 ? 4 : 2))
void gemm_bt_kernel(const bf16s* __restrict__ A, const bf16s* __restrict__ Bt,
                    const float* __restrict__ bias, void* __restrict__ Cp,
                    int M, int N, int K)
{
    constexpr int BN = 128;
    constexpr int WR = BM / 64;
    constexpr int WC = 4 / WR;
    constexpr int TN = BN / WC;
    constexpr int NF = TN / 16;
    constexpr int NSUB = BK / 32;        // 32-deep subtiles per buffer
    constexpr int RA = BM / 64;          // A staging rounds per subtile
    constexpr int ASUB = BM * 32;        // shorts per A subtile
    constexpr int BSUB = BN * 32;
    constexpr int ASZ = NSUB * ASUB;
    constexpr int BSZ = NSUB * BSUB;

    __shared__ short As[2 * ASZ];
    __shared__ short Bs[2 * BSZ];

    const int t = threadIdx.x, lane = t & 63, wave = t >> 6;
    const int g = lane >> 4, ln16 = lane & 15;
    const int wr = wave / WC, wc = wave % WC;
    const int rowA0 = blockIdx.y * BM, rowB0 = blockIdx.x * BN;

    const bf16s* Ab = A + (size_t)rowA0 * K;
    const bf16s* Bb = Bt + (size_t)rowB0 * K;

    f32x4 acc[4][NF] = {};

    auto stage = [&](int buf, int k0) {
        short* Ad = As + buf * ASZ;
        short* Bd = Bs + buf * BSZ;
#pragma unroll
        for (int s = 0; s < NSUB; ++s) {
#pragma unroll
            for (int rnd = 0; rnd < RA; ++rnd) {
                int p = rnd * 256 + t;
                int sr = p >> 3, c3 = (p & 7) ^ (sr & 7);
                int r = sr * 2 + (c3 >> 2), c = c3 & 3;
                gload_lds16(Ab + (size_t)r * K + k0 + s * 32 + c * 8,
                            Ad + s * ASUB + (rnd * 256 + wave * 64) * 8);
            }
#pragma unroll
            for (int rnd = 0; rnd < 2; ++rnd) {
                int p = rnd * 256 + t;
                int sr = p >> 3, c3 = (p & 7) ^ (sr & 7);
                int r = sr * 2 + (c3 >> 2), c = c3 & 3;
                gload_lds16(Bb + (size_t)r * K + k0 + s * 32 + c * 8,
                            Bd + s * BSUB + (rnd * 256 + wave * 64) * 8);
            }
        }
    };

    stage(0, 0);
    __syncthreads();                    // drains vmcnt(0) + barrier
    int cur = 0;
    for (int k0 = 0; k0 < K; k0 += BK) {
        if (k0 + BK < K) stage(cur ^ 1, k0 + BK);   // prefetch next K-tile
        const short* Ar0 = As + cur * ASZ;
        const short* Br0 = Bs + cur * BSZ;
#pragma unroll
        for (int s = 0; s < NSUB; ++s) {
            const short* Ar = Ar0 + s * ASUB;
            const short* Br = Br0 + s * BSUB;
            bf16x8 af[4], bfr[NF];
#pragma unroll
            for (int m = 0; m < 4; ++m) {
                int r = wr * 64 + m * 16 + ln16;
                int sr = r >> 1, c3 = (r & 1) * 4 + g;
                af[m] = *(const bf16x8*)(Ar + sr * 64 + ((c3 ^ (sr & 7)) * 8));
            }
#pragma unroll
            for (int n = 0; n < NF; ++n) {
                int r = wc * TN + n * 16 + ln16;
                int sr = r >> 1, c3 = (r & 1) * 4 + g;
                bfr[n] = *(const bf16x8*)(Br + sr * 64 + ((c3 ^ (sr & 7)) * 8));
            }
#pragma unroll
            for (int m = 0; m < 4; ++m)
#pragma unroll
                for (int n = 0; n < NF; ++n)
                    acc[m][n] = mfma16(af[m], bfr[n], acc[m][n]);
        }
        __syncthreads();                // next buffer staged + all reads done
        cur ^= 1;
    }

    const int row0 = rowA0 + wr * 64, col0 = rowB0 + wc * TN;
#pragma unroll
    for (int n = 0; n < NF; ++n) {
        const int col = col0 + n * 16 + ln16;
        const float bv = bias[col];
#pragma unroll
        for (int m = 0; m < 4; ++m) {
#pragma unroll
            for (int r = 0; r < 4; ++r) {
                int row = row0 + m * 16 + g * 4 + r;
                float v = acc[m][n][r] + bv;
                if (RELU) v = fmaxf(v, 0.f);
                if (OUT_BF16) ((bf16s*)Cp)[(size_t)row * N + col] = f2b(v);
                else          ((float*)Cp)[(size_t)row * N + col] = v;
            }
        }
    }
}

// ---------------------------------------------------------------------------
// Flash attention (unchanged from r7): transposed softmax, conflict-free P,
// defer-max, XCD-aware swizzle.
// ---------------------------------------------------------------------------
template<int CAUSAL>
__global__ __launch_bounds__(256, 4)
void flash_kernel(const bf16s* __restrict__ Q, int ldq,
                  const bf16s* __restrict__ K, int ldk,
                  const bf16s* __restrict__ Vt,
                  bf16s* __restrict__ O, int ldo,
                  int Sq, int Sk, float scale)
{
    __shared__ short Ks[2 * 64 * 64];
    __shared__ short Vs[2 * 64 * 64];
    __shared__ short Ps[4 * 16 * 64];
    const int t = threadIdx.x, lane = t & 63, wave = t >> 6;
    const int g = lane >> 4, ln16 = lane & 15;

    // XCD-aware decode: id = (bh-major within XCD) * 8 + xcd
    const int nqt = Sq >> 6;                       // 32
    const int id = blockIdx.x;
    const int perx = gridDim.x >> 3;               // blocks per XCD slot
    const int bhPerX = perx / nqt;                 // bh columns per XCD
    const int idx = id >> 3;
    const int bh = (id & 7) * bhPerX + idx / nqt;
    int qt = idx % nqt;
    if (CAUSAL) qt = nqt - 1 - qt;                 // heavy q-tiles first
    const int b = bh >> 4, h = bh & 15;
    const int q0 = qt * 64;
    const float sc2 = scale * 1.44269504f;         // exp2-domain scale
    const float thrRaw = 8.0f / sc2;               // defer-max threshold (raw)

    bf16x8 aq[2];
    {
        const size_t qrow = (size_t)(b * Sq + q0 + wave * 16 + ln16);
#pragma unroll
        for (int kk = 0; kk < 2; ++kk)
            aq[kk] = *(const bf16x8*)(Q + qrow * ldq + h * 64 + kk * 32 + g * 8);
    }

    float m_raw = -1e30f, l_sum = 0.f;   // stats for q = ln16 (this wave)
    f32x4 oa[4] = {};

    const int nkt = CAUSAL ? (qt + 1) : (Sk >> 6);
    const bf16s* Kbase = K + (size_t)b * Sk * ldk + h * 64;
    const bf16s* Vbase = Vt + (size_t)bh * 64 * Sk;
    short* myP = Ps + wave * 1024;

    auto stage = [&](int buf, int kt) {
        const bf16s* ksrc = Kbase + (size_t)(kt * 64) * ldk;
        const bf16s* vsrc = Vbase + kt * 64;
        short* Kd = Ks + buf * 4096;
        short* Vd = Vs + buf * 4096;
#pragma unroll
        for (int rnd = 0; rnd < 2; ++rnd) {
            int p = rnd * 256 + t;
            int r = p >> 3, c = (p & 7) ^ (r & 7);
            gload_lds16(ksrc + (size_t)r * ldk + c * 8,
                        Kd + (rnd * 256 + wave * 64) * 8);
        }
#pragma unroll
        for (int rnd = 0; rnd < 2; ++rnd) {
            int p = rnd * 256 + t;
            int r = p >> 3, c = (p & 7) ^ (r & 7);
            gload_lds16(vsrc + (size_t)r * Sk + c * 8,
                        Vd + (rnd * 256 + wave * 64) * 8);
        }
    };

    stage(0, 0);
    __syncthreads();
    int cur = 0;

    for (int kt = 0; kt < nkt; ++kt) {
        if (kt + 1 < nkt) stage(cur ^ 1, kt + 1);
        const short* Kr = Ks + cur * 4096;
        const short* Vr = Vs + cur * 4096;

        // ---- S^T = K Q^T: lane holds q=ln16, keys n*16+g*4+r (raw) ----
        f32x4 sa[4] = {};
        __builtin_amdgcn_s_setprio(1);
#pragma unroll
        for (int kk = 0; kk < 2; ++kk) {
#pragma unroll
            for (int n = 0; n < 4; ++n) {
                int key = n * 16 + ln16;
                bf16x8 ak = *(const bf16x8*)(Kr + key * 64 +
                                             (((kk * 4 + g) ^ (key & 7)) * 8));
                sa[n] = mfma16(ak, aq[kk], sa[n]);
            }
        }
        __builtin_amdgcn_s_setprio(0);

        float sv[4][4];
        const bool diag = CAUSAL && (kt == qt);
#pragma unroll
        for (int n = 0; n < 4; ++n)
#pragma unroll
            for (int r = 0; r < 4; ++r) {
                float s = sa[n][r];
                if (diag && (n * 16 + g * 4 + r > wave * 16 + ln16)) s = -1e30f;
                sv[n][r] = s;
            }

        // ---- row max: in-lane tree + cross-g (2 shuffles) ----
        float rm = fmaxf(
            fmaxf(fmaxf(fmaxf(sv[0][0], sv[0][1]), fmaxf(sv[0][2], sv[0][3])),
                  fmaxf(fmaxf(sv[1][0], sv[1][1]), fmaxf(sv[1][2], sv[1][3]))),
            fmaxf(fmaxf(fmaxf(sv[2][0], sv[2][1]), fmaxf(sv[2][2], sv[2][3])),
                  fmaxf(fmaxf(sv[3][0], sv[3][1]), fmaxf(sv[3][2], sv[3][3]))));
        rm = fmaxf(rm, __shfl_xor(rm, 16, 64));
        rm = fmaxf(rm, __shfl_xor(rm, 32, 64));

        // ---- defer-max (T13): only rescale when max grew past headroom ----
        if (!__all(rm <= m_raw + thrRaw)) {
            const float mnew = fmaxf(m_raw, rm);
            const float al = exp2f((m_raw - mnew) * sc2);
            m_raw = mnew;
            l_sum *= al;
            float alr[4];
#pragma unroll
            for (int r = 0; r < 4; ++r)
                alr[r] = __shfl(al, g * 4 + r, 64);
#pragma unroll
            for (int n = 0; n < 4; ++n)
#pragma unroll
                for (int r = 0; r < 4; ++r)
                    oa[n][r] *= alr[r];
        }
        const float nm = -m_raw * sc2;

        float rs = 0.f;
#pragma unroll
        for (int n = 0; n < 4; ++n)
#pragma unroll
            for (int r = 0; r < 4; ++r) {
                float p = exp2f(fmaf(sv[n][r], sc2, nm));
                sv[n][r] = p;
                rs += p;
            }
        rs += __shfl_xor(rs, 16, 64);
        rs += __shfl_xor(rs, 32, 64);
        l_sum += rs;

        // ---- P -> LDS: 4x b64, chunk ^ (q&7), half ^ (q>>3): bank-clean ----
#pragma unroll
        for (int n = 0; n < 4; ++n) {
            uint2 w;
            w.x = pk2(sv[n][0], sv[n][1]);
            w.y = pk2(sv[n][2], sv[n][3]);
            int c = n * 2 + (g >> 1);
            int sh = ln16 * 64 + ((c ^ (ln16 & 7)) * 8) +
                     (((g & 1) ^ (ln16 >> 3)) * 4);
            *(uint2*)(myP + sh) = w;
        }
        asm volatile("s_waitcnt lgkmcnt(0)" ::: "memory");

        // ---- O += P @ V ----
        __builtin_amdgcn_s_setprio(1);
#pragma unroll
        for (int kk = 0; kk < 2; ++kk) {
            const int base = ln16 * 64 + (((kk * 4 + g) ^ (ln16 & 7)) * 8);
            const int x0 = (ln16 >> 3) * 4;
            union { bf16x8 v; uint2 u2[2]; } pu;
            pu.u2[0] = *(const uint2*)(myP + base + x0);        // logical half 0
            pu.u2[1] = *(const uint2*)(myP + base + (x0 ^ 4));  // logical half 1
            bf16x8 pa = pu.v;
#pragma unroll
            for (int n = 0; n < 4; ++n) {
                int d = n * 16 + ln16;
                bf16x8 vb = *(const bf16x8*)(Vr + d * 64 +
                                             (((kk * 4 + g) ^ (d & 7)) * 8));
                oa[n] = mfma16(pa, vb, oa[n]);
            }
        }
        __builtin_amdgcn_s_setprio(0);
        __syncthreads();
        cur ^= 1;
    }

    const float inv = 1.f / l_sum;
    float invr[4];
#pragma unroll
    for (int r = 0; r < 4; ++r)
        invr[r] = __shfl(inv, g * 4 + r, 64);
#pragma unroll
    for (int n = 0; n < 4; ++n)
#pragma unroll
        for (int r = 0; r < 4; ++r) {
            int q = q0 + wave * 16 + g * 4 + r;
            int d = h * 64 + n * 16 + ln16;
            O[(size_t)(b * Sq + q) * ldo + d] = f2b(oa[n][r] * invr[r]);
        }
}

// ---------------------------------------------------------------------------
// y = LN(x + a) * g + b   (D=1024, one block/row, fp32), opt bf16 copy out
// ---------------------------------------------------------------------------
template<int WRITE_BF16>
__global__ __launch_bounds__(256)
void add_ln_kernel(const float* __restrict__ X, const float* __restrict__ A,
                   const float* __restrict__ G, const float* __restrict__ Bb,
                   float* __restrict__ Y, bf16s* __restrict__ Yb)
{
    const int row = blockIdx.x, t = threadIdx.x;
    const int lane = t & 63, w = t >> 6;
    const size_t base = (size_t)row * 1024 + t * 4;
    const float4 xv = *(const float4*)(X + base);
    const float4 av = *(const float4*)(A + base);
    float4 v;
    v.x = xv.x + av.x; v.y = xv.y + av.y; v.z = xv.z + av.z; v.w = xv.w + av.w;
    float s = v.x + v.y + v.z + v.w;
    float q = v.x * v.x + v.y * v.y + v.z * v.z + v.w * v.w;
#pragma unroll
    for (int x = 1; x < 64; x <<= 1) {
        s += __shfl_xor(s, x, 64);
        q += __shfl_xor(q, x, 64);
    }
    __shared__ float red[8];
    if (lane == 0) { red[w] = s; red[4 + w] = q; }
    __syncthreads();
    s = red[0] + red[1] + red[2] + red[3];
    q = red[4] + red[5] + red[6] + red[7];
    const float mu = s * (1.f / 1024.f);
    const float var = q * (1.f / 1024.f) - mu * mu;
    const float rstd = rsqrtf(var + 1e-5f);
    const float4 gv = *(const float4*)(G + t * 4);
    const float4 bv = *(const float4*)(Bb + t * 4);
    float o0 = (v.x - mu) * rstd * gv.x + bv.x;
    float o1 = (v.y - mu) * rstd * gv.y + bv.y;
    float o2 = (v.z - mu) * rstd * gv.z + bv.z;
    float o3 = (v.w - mu) * rstd * gv.w + bv.w;
    float4 ov; ov.x = o0; ov.y = o1; ov.z = o2; ov.w = o3;
    *(float4*)(Y + base) = ov;
    if (WRITE_BF16) {
        short4 yb;
        yb.x = f2b(o0); yb.y = f2b(o1); yb.z = f2b(o2); yb.w = f2b(o3);
        *(short4*)(Yb + base) = yb;
    }
}

// ---------------------------------------------------------------------------
// launch
// ---------------------------------------------------------------------------
extern "C" void kernel_launch(void* const* d_in, const int* in_sizes, int n_in,
                              void* d_out, int out_size, void* d_ws, size_t ws_size,
                              hipStream_t stream)
{
    constexpr int Dm = 1024, DFF = 4096, Bq = 2, S = 2048;
    constexpr int NT = Bq * S;   // 4096 tokens
    constexpr size_t MM = (size_t)Dm * Dm;

    const float* x    = (const float*)d_in[0];
    const float* enc  = (const float*)d_in[1];
    const float* s_wq = (const float*)d_in[4];  const float* s_bq = (const float*)d_in[5];
    const float* s_wk = (const float*)d_in[6];  const float* s_bk = (const float*)d_in[7];
    const float* s_wv = (const float*)d_in[8];  const float* s_bv = (const float*)d_in[9];
    const float* s_wo = (const float*)d_in[10]; const float* s_bo = (const float*)d_in[11];
    const float* c_wq = (const float*)d_in[12]; const float* c_bq = (const float*)d_in[13];
    const float* c_wk = (const float*)d_in[14]; const float* c_bk = (const float*)d_in[15];
    const float* c_wv = (const float*)d_in[16]; const float* c_bv = (const float*)d_in[17];
    const float* c_wo = (const float*)d_in[18]; const float* c_bo = (const float*)d_in[19];
    const float* ffw1 = (const float*)d_in[20]; const float* ffb1 = (const float*)d_in[21];
    const float* ffw2 = (const float*)d_in[22]; const float* ffb2 = (const float*)d_in[23];
    const float* ln1g = (const float*)d_in[24]; const float* ln1b = (const float*)d_in[25];
    const float* ln2g = (const float*)d_in[26]; const float* ln2b = (const float*)d_in[27];
    const float* ln3g = (const float*)d_in[28]; const float* ln3b = (const float*)d_in[29];

    char* ws = (char*)d_ws;
    size_t off = 0;
    auto alloc = [&](size_t bytes) -> char* {
        char* p = ws + off;
        off += (bytes + 255) & ~(size_t)255;
        return p;
    };

    bf16s* xbf   = (bf16s*)alloc((size_t)NT * Dm * 2);
    bf16s* encbf = (bf16s*)alloc((size_t)NT * Dm * 2);   // contiguous with xbf
    bf16s* wAll  = (bf16s*)alloc(8 * MM * 2);            // 8 transposed 1024^2 weights
    bf16s* w1T   = (bf16s*)alloc((size_t)Dm * DFF * 2);
    bf16s* w2T   = (bf16s*)alloc((size_t)Dm * DFF * 2);
    float* bqkv  = (float*)alloc((size_t)3 * Dm * 4);
    float* bkvc  = (float*)alloc((size_t)2 * Dm * 4);
    bf16s* QKV   = (bf16s*)alloc((size_t)NT * 3 * Dm * 2);  // reused: Q2 + KV2
    bf16s* Vt    = (bf16s*)alloc((size_t)NT * Dm * 2);      // reused: V2t
    bf16s* AO    = (bf16s*)alloc((size_t)NT * Dm * 2);      // reused: AO2
    float* Pbuf  = (float*)alloc((size_t)NT * Dm * 4);      // reused: P1/P2/F
    float* x1f   = (float*)alloc((size_t)NT * Dm * 4);
    bf16s* x1bf  = (bf16s*)alloc((size_t)NT * Dm * 2);
    float* x2f   = (float*)alloc((size_t)NT * Dm * 4);
    bf16s* x2bf  = (bf16s*)alloc((size_t)NT * Dm * 2);
    bf16s* Hbuf  = (bf16s*)alloc((size_t)NT * DFF * 2);
    (void)ws_size; (void)in_sizes; (void)n_in; (void)out_size;

    bf16s* wqkvT = wAll;            // slots 0,1,2: s_wq, s_wk, s_wv
    bf16s* woTs  = wAll + 3 * MM;   // slot 3
    bf16s* wqTc  = wAll + 4 * MM;   // slot 4
    bf16s* wkvTc = wAll + 5 * MM;   // slots 5,6: c_wk, c_wv
    bf16s* woTc  = wAll + 7 * MM;   // slot 7

    // ---- phase 0: casts / transposes / bias concat ----
    cast2_f32_bf16_kernel<<<2 * NT * Dm / 8 / 256, 256, 0, stream>>>(
        x, enc, xbf, NT * Dm);
    P8 srcs = {{s_wq, s_wk, s_wv, s_wo, c_wq, c_wk, c_wv, c_wo}};
    transpose_cast8_kernel<<<dim3(16, 16, 8), 256, 0, stream>>>(srcs, wAll);
    transpose_cast_kernel<<<dim3(64, 16), 256, 0, stream>>>(ffw1, w1T, Dm, DFF);
    transpose_cast_kernel<<<dim3(16, 64), 256, 0, stream>>>(ffw2, w2T, DFF, Dm);
    concat3_kernel<<<4, 256, 0, stream>>>(s_bq, s_bk, s_bv, bqkv, Dm);
    concat2_kernel<<<4, 256, 0, stream>>>(c_bk, c_bv, bkvc, Dm);

    // ---- phase 1: self-attention ----
    gemm_bt_kernel<128, 64, 1, 0><<<dim3(24, 32), 256, 0, stream>>>(
        xbf, wqkvT, bqkv, QKV, NT, 3 * Dm, Dm);
    transpose_v_kernel<<<dim3(32, 32), 256, 0, stream>>>(
        QKV + 2 * Dm, 3 * Dm, Vt, S);
    flash_kernel<1><<<dim3(1024), 256, 0, stream>>>(
        QKV, 3 * Dm, QKV + Dm, 3 * Dm, Vt, AO, Dm, S, S, 0.125f);
    gemm_bt_kernel<64, 32, 0, 0><<<dim3(8, 64), 256, 0, stream>>>(
        AO, woTs, s_bo, Pbuf, NT, Dm, Dm);
    add_ln_kernel<1><<<NT, 256, 0, stream>>>(x, Pbuf, ln1g, ln1b, x1f, x1bf);

    // ---- phase 2: cross-attention ----
    bf16s* Q2  = QKV;
    bf16s* KV2 = QKV + (size_t)NT * Dm;
    gemm_bt_kernel<64, 32, 1, 0><<<dim3(8, 64), 256, 0, stream>>>(
        x1bf, wqTc, c_bq, Q2, NT, Dm, Dm);
    gemm_bt_kernel<128, 64, 1, 0><<<dim3(16, 32), 256, 0, stream>>>(
        encbf, wkvTc, bkvc, KV2, NT, 2 * Dm, Dm);
    transpose_v_kernel<<<dim3(32, 32), 256, 0, stream>>>(
        KV2 + Dm, 2 * Dm, Vt, S);
    flash_kernel<0><<<dim3(1024), 256, 0, stream>>>(
        Q2, Dm, KV2, 2 * Dm, Vt, AO, Dm, S, S, 0.125f);
    gemm_bt_kernel<64, 32, 0, 0><<<dim3(8, 64), 256, 0, stream>>>(
        AO, woTc, c_bo, Pbuf, NT, Dm, Dm);
    add_ln_kernel<1><<<NT, 256, 0, stream>>>(x1f, Pbuf, ln2g, ln2b, x2f, x2bf);

    // ---- phase 3: FFN ----
    gemm_bt_kernel<128, 64, 1, 1><<<dim3(32, 32), 256, 0, stream>>>(
        x2bf, w1T, ffb1, Hbuf, NT, DFF, Dm);
    gemm_bt_kernel<64, 32, 0, 0><<<dim3(8, 64), 256, 0, stream>>>(
        Hbuf, w2T, ffb2, Pbuf, NT, Dm, DFF);
    add_ln_kernel<0><<<NT, 256, 0, stream>>>(
        x2f, Pbuf, ln3g, ln3b, (float*)d_out, nullptr);
}

// Round 11
// 576.910 us; speedup vs baseline: 1.0878x; 1.0519x over previous
//
#include <hip/hip_runtime.h>
#include <hip/hip_bf16.h>
#include <stdint.h>

// ---------------------------------------------------------------------------
// DecoderLayer fused pipeline, round 11.
// Changes vs r8 (flash only; GEMM(BK=64)/LN/prep identical):
//  - causal load-balance: zigzag qt (heavy/light interleave) so any 4
//    consecutive blocks on a CU sum to ~equal tile-work
//  - all lane-constant LDS offsets hoisted out of the k-loop (one shared
//    offset table for K and V reads); running global src pointers
//  - native exp2 (__builtin_amdgcn_exp2f); max3-fusable row-max chain
// ---------------------------------------------------------------------------

#define DEV static __device__ __forceinline__

typedef short bf16s;                                        // bf16 storage
typedef __attribute__((ext_vector_type(8))) short bf16x8;   // MFMA A/B frag
typedef __attribute__((ext_vector_type(4))) float f32x4;    // MFMA C/D frag

DEV short f2b(float f) {
    union { __hip_bfloat16 h; short s; } u;
    u.h = __float2bfloat16(f);
    return u.s;
}

DEV unsigned pk2(float lo, float hi) {
    union { __hip_bfloat162 h; unsigned u; } u;
    u.h = __float22bfloat162_rn(float2{lo, hi});
    return u.u;
}

DEV f32x4 mfma16(bf16x8 a, bf16x8 b, f32x4 c) {
    return __builtin_amdgcn_mfma_f32_16x16x32_bf16(a, b, c, 0, 0, 0);
}

DEV void gload_lds16(const bf16s* g, short* l) {
    __builtin_amdgcn_global_load_lds(
        (const __attribute__((address_space(1))) void*)g,
        (__attribute__((address_space(3))) void*)l,
        16, 0, 0);
}

// ---------------------------------------------------------------------------
// cast fp32 -> bf16 for x and enc in one launch (outputs contiguous)
// ---------------------------------------------------------------------------
__global__ __launch_bounds__(256) void cast2_f32_bf16_kernel(
    const float* __restrict__ a, const float* __restrict__ b,
    bf16s* __restrict__ out, int n)
{
    int i = (blockIdx.x * 256 + threadIdx.x) * 8;
    const float* src = (i < n) ? a : b;
    int j = (i < n) ? i : i - n;
    const float4 u = *(const float4*)(src + j);
    const float4 v = *(const float4*)(src + j + 4);
    bf16x8 r;
    r[0] = f2b(u.x); r[1] = f2b(u.y); r[2] = f2b(u.z); r[3] = f2b(u.w);
    r[4] = f2b(v.x); r[5] = f2b(v.y); r[6] = f2b(v.z); r[7] = f2b(v.w);
    *(bf16x8*)(out + i) = r;
}

// ---------------------------------------------------------------------------
// 8x (1024x1024) W fp32 [K][N] -> Wt bf16 [N][K], one launch, z = slot
// ---------------------------------------------------------------------------
struct P8 { const float* p[8]; };

__global__ __launch_bounds__(256) void transpose_cast8_kernel(
    P8 srcs, bf16s* __restrict__ dst)
{
    __shared__ short tile[64][65];
    const float* W = srcs.p[blockIdx.z];
    bf16s* Wt = dst + (size_t)blockIdx.z * 1024 * 1024;
    const int n0 = blockIdx.x * 64, k0 = blockIdx.y * 64;
    const int t = threadIdx.x;
#pragma unroll
    for (int it = 0; it < 16; ++it) {
        int idx = it * 256 + t;
        int r = idx >> 6, c = idx & 63;
        tile[r][c] = f2b(W[(size_t)(k0 + r) * 1024 + n0 + c]);
    }
    __syncthreads();
#pragma unroll
    for (int it = 0; it < 16; ++it) {
        int idx = it * 256 + t;
        int r = idx >> 6, c = idx & 63;
        Wt[(size_t)(n0 + r) * 1024 + k0 + c] = tile[c][r];
    }
}

// generic single transpose (FFN weights)
__global__ __launch_bounds__(256) void transpose_cast_kernel(
    const float* __restrict__ W, bf16s* __restrict__ Wt, int Krows, int Ncols)
{
    __shared__ short tile[64][65];
    const int n0 = blockIdx.x * 64, k0 = blockIdx.y * 64;
    const int t = threadIdx.x;
#pragma unroll
    for (int it = 0; it < 16; ++it) {
        int idx = it * 256 + t;
        int r = idx >> 6, c = idx & 63;
        tile[r][c] = f2b(W[(size_t)(k0 + r) * Ncols + n0 + c]);
    }
    __syncthreads();
#pragma unroll
    for (int it = 0; it < 16; ++it) {
        int idx = it * 256 + t;
        int r = idx >> 6, c = idx & 63;
        Wt[(size_t)(n0 + r) * Krows + k0 + c] = tile[c][r];
    }
}

// ---------------------------------------------------------------------------
// V bf16 [rows][ldv] (col-offset pre-added) -> Vt bf16 [B*NH][64][Sk]
// ---------------------------------------------------------------------------
__global__ __launch_bounds__(256) void transpose_v_kernel(
    const bf16s* __restrict__ V, int ldv, bf16s* __restrict__ Vt, int Sk)
{
    __shared__ short tile[64][65];
    const int s0 = blockIdx.x * 64;
    const int bh = blockIdx.y, b = bh >> 4, h = bh & 15;
    const int t = threadIdx.x;
#pragma unroll
    for (int it = 0; it < 16; ++it) {
        int idx = it * 256 + t;
        int r = idx >> 6, c = idx & 63;
        tile[r][c] = V[(size_t)(b * Sk + s0 + r) * ldv + h * 64 + c];
    }
    __syncthreads();
#pragma unroll
    for (int it = 0; it < 16; ++it) {
        int idx = it * 256 + t;
        int r = idx >> 6, c = idx & 63;
        Vt[((size_t)bh * 64 + r) * Sk + s0 + c] = tile[c][r];
    }
}

// ---------------------------------------------------------------------------
// bias concat helpers
// ---------------------------------------------------------------------------
__global__ void concat3_kernel(const float* a, const float* b, const float* c,
                               float* o, int n)
{
    int i = blockIdx.x * 256 + threadIdx.x;
    if (i < n) { o[i] = a[i]; o[n + i] = b[i]; o[2 * n + i] = c[i]; }
}
__global__ void concat2_kernel(const float* a, const float* b, float* o, int n)
{
    int i = blockIdx.x * 256 + threadIdx.x;
    if (i < n) { o[i] = a[i]; o[n + i] = b[i]; }
}

// ---------------------------------------------------------------------------
// GEMM (unchanged from r8): 2-phase prefetch, double-buffered LDS, BK subtiles.
// ---------------------------------------------------------------------------
template<int BM, int BK, int OUT_BF16, int RELU>
__global__ __launch_bounds__(256, (BM == 64 ? 4 : 2))
void gemm_bt_kernel(const bf16s* __restrict__ A, const bf16s* __restrict__ Bt,
                    const float* __restrict__ bias, void* __restrict__ Cp,
                    int M, int N, int K)
{
    constexpr int BN = 128;
    constexpr int WR = BM / 64;
    constexpr int WC = 4 / WR;
    constexpr int TN = BN / WC;
    constexpr int NF = TN / 16;
    constexpr int NSUB = BK / 32;
    constexpr int RA = BM / 64;
    constexpr int ASUB = BM * 32;
    constexpr int BSUB = BN * 32;
    constexpr int ASZ = NSUB * ASUB;
    constexpr int BSZ = NSUB * BSUB;

    __shared__ short As[2 * ASZ];
    __shared__ short Bs[2 * BSZ];

    const int t = threadIdx.x, lane = t & 63, wave = t >> 6;
    const int g = lane >> 4, ln16 = lane & 15;
    const int wr = wave / WC, wc = wave % WC;
    const int rowA0 = blockIdx.y * BM, rowB0 = blockIdx.x * BN;

    const bf16s* Ab = A + (size_t)rowA0 * K;
    const bf16s* Bb = Bt + (size_t)rowB0 * K;

    f32x4 acc[4][NF] = {};

    auto stage = [&](int buf, int k0) {
        short* Ad = As + buf * ASZ;
        short* Bd = Bs + buf * BSZ;
#pragma unroll
        for (int s = 0; s < NSUB; ++s) {
#pragma unroll
            for (int rnd = 0; rnd < RA; ++rnd) {
                int p = rnd * 256 + t;
                int sr = p >> 3, c3 = (p & 7) ^ (sr & 7);
                int r = sr * 2 + (c3 >> 2), c = c3 & 3;
                gload_lds16(Ab + (size_t)r * K + k0 + s * 32 + c * 8,
                            Ad + s * ASUB + (rnd * 256 + wave * 64) * 8);
            }
#pragma unroll
            for (int rnd = 0; rnd < 2; ++rnd) {
                int p = rnd * 256 + t;
                int sr = p >> 3, c3 = (p & 7) ^ (sr & 7);
                int r = sr * 2 + (c3 >> 2), c = c3 & 3;
                gload_lds16(Bb + (size_t)r * K + k0 + s * 32 + c * 8,
                            Bd + s * BSUB + (rnd * 256 + wave * 64) * 8);
            }
        }
    };

    stage(0, 0);
    __syncthreads();
    int cur = 0;
    for (int k0 = 0; k0 < K; k0 += BK) {
        if (k0 + BK < K) stage(cur ^ 1, k0 + BK);
        const short* Ar0 = As + cur * ASZ;
        const short* Br0 = Bs + cur * BSZ;
#pragma unroll
        for (int s = 0; s < NSUB; ++s) {
            const short* Ar = Ar0 + s * ASUB;
            const short* Br = Br0 + s * BSUB;
            bf16x8 af[4], bfr[NF];
#pragma unroll
            for (int m = 0; m < 4; ++m) {
                int r = wr * 64 + m * 16 + ln16;
                int sr = r >> 1, c3 = (r & 1) * 4 + g;
                af[m] = *(const bf16x8*)(Ar + sr * 64 + ((c3 ^ (sr & 7)) * 8));
            }
#pragma unroll
            for (int n = 0; n < NF; ++n) {
                int r = wc * TN + n * 16 + ln16;
                int sr = r >> 1, c3 = (r & 1) * 4 + g;
                bfr[n] = *(const bf16x8*)(Br + sr * 64 + ((c3 ^ (sr & 7)) * 8));
            }
#pragma unroll
            for (int m = 0; m < 4; ++m)
#pragma unroll
                for (int n = 0; n < NF; ++n)
                    acc[m][n] = mfma16(af[m], bfr[n], acc[m][n]);
        }
        __syncthreads();
        cur ^= 1;
    }

    const int row0 = rowA0 + wr * 64, col0 = rowB0 + wc * TN;
#pragma unroll
    for (int n = 0; n < NF; ++n) {
        const int col = col0 + n * 16 + ln16;
        const float bv = bias[col];
#pragma unroll
        for (int m = 0; m < 4; ++m) {
#pragma unroll
            for (int r = 0; r < 4; ++r) {
                int row = row0 + m * 16 + g * 4 + r;
                float v = acc[m][n][r] + bv;
                if (RELU) v = fmaxf(v, 0.f);
                if (OUT_BF16) ((bf16s*)Cp)[(size_t)row * N + col] = f2b(v);
                else          ((float*)Cp)[(size_t)row * N + col] = v;
            }
        }
    }
}

// ---------------------------------------------------------------------------
// Flash attention: transposed softmax, conflict-free P, defer-max, XCD swz,
// zigzag causal balance, hoisted LDS offsets, native exp2.
// ---------------------------------------------------------------------------
template<int CAUSAL>
__global__ __launch_bounds__(256, 4)
void flash_kernel(const bf16s* __restrict__ Q, int ldq,
                  const bf16s* __restrict__ K, int ldk,
                  const bf16s* __restrict__ Vt,
                  bf16s* __restrict__ O, int ldo,
                  int Sq, int Sk, float scale)
{
    __shared__ short Ks[2 * 64 * 64];
    __shared__ short Vs[2 * 64 * 64];
    __shared__ short Ps[4 * 16 * 64];
    const int t = threadIdx.x, lane = t & 63, wave = t >> 6;
    const int g = lane >> 4, ln16 = lane & 15;

    // XCD-aware decode + causal zigzag (heavy/light interleave)
    const int nqt = Sq >> 6;                       // 32
    const int id = blockIdx.x;
    const int perx = gridDim.x >> 3;               // blocks per XCD slot
    const int bhPerX = perx / nqt;                 // bh columns per XCD
    const int idx = id >> 3;
    const int bh = (id & 7) * bhPerX + idx / nqt;
    const int j = idx % nqt;
    const int qt = CAUSAL ? ((j & 1) ? (j >> 1) : (nqt - 1 - (j >> 1))) : j;
    const int b = bh >> 4, h = bh & 15;
    const int q0 = qt * 64;
    const float sc2 = scale * 1.44269504f;         // exp2-domain scale
    const float thrRaw = 8.0f / sc2;               // defer-max threshold (raw)

    bf16x8 aq[2];
    {
        const size_t qrow = (size_t)(b * Sq + q0 + wave * 16 + ln16);
#pragma unroll
        for (int kk = 0; kk < 2; ++kk)
            aq[kk] = *(const bf16x8*)(Q + qrow * ldq + h * 64 + kk * 32 + g * 8);
    }

    // ---- hoisted lane-constant LDS offsets (shorts) ----
    int qvOff[2][4];        // K-read and V-read share the same formula
    int paOff[2];           // P A-frag read base
    int pWr[4];             // P write offsets
#pragma unroll
    for (int kk = 0; kk < 2; ++kk) {
        paOff[kk] = ln16 * 64 + (((kk * 4 + g) ^ (ln16 & 7)) * 8);
#pragma unroll
        for (int n = 0; n < 4; ++n) {
            int key = n * 16 + ln16;
            qvOff[kk][n] = key * 64 + (((kk * 4 + g) ^ (key & 7)) * 8);
        }
    }
#pragma unroll
    for (int n = 0; n < 4; ++n) {
        int c = n * 2 + (g >> 1);
        pWr[n] = ln16 * 64 + ((c ^ (ln16 & 7)) * 8) +
                 (((g & 1) ^ (ln16 >> 3)) * 4);
    }
    const int x0 = (ln16 >> 3) * 4;

    // hoisted staging offsets (lane-constant)
    int sgOffK[2], sgOffV[2], sgLds[2];
#pragma unroll
    for (int rnd = 0; rnd < 2; ++rnd) {
        int p = rnd * 256 + t;
        int r = p >> 3, c = (p & 7) ^ (r & 7);
        sgOffK[rnd] = r * ldk + c * 8;
        sgOffV[rnd] = r * Sk + c * 8;
        sgLds[rnd]  = (rnd * 256 + wave * 64) * 8;
    }

    float m_raw = -1e30f, l_sum = 0.f;   // stats for q = ln16 (this wave)
    f32x4 oa[4] = {};

    const int nkt = CAUSAL ? (qt + 1) : (Sk >> 6);
    const bf16s* kcur = K + (size_t)b * Sk * ldk + h * 64;   // advances 64*ldk/tile
    const bf16s* vcur = Vt + (size_t)bh * 64 * Sk;           // advances 64/tile
    short* myP = Ps + wave * 1024;

    auto stage = [&](int buf) {
        short* Kd = Ks + (buf << 12);
        short* Vd = Vs + (buf << 12);
#pragma unroll
        for (int rnd = 0; rnd < 2; ++rnd)
            gload_lds16(kcur + sgOffK[rnd], Kd + sgLds[rnd]);
#pragma unroll
        for (int rnd = 0; rnd < 2; ++rnd)
            gload_lds16(vcur + sgOffV[rnd], Vd + sgLds[rnd]);
    };

    stage(0);
    kcur += (size_t)64 * ldk; vcur += 64;
    __syncthreads();
    int cur = 0;

    for (int kt = 0; kt < nkt; ++kt) {
        if (kt + 1 < nkt) {
            stage(cur ^ 1);
            kcur += (size_t)64 * ldk; vcur += 64;
        }
        const short* Kr = Ks + (cur << 12);
        const short* Vr = Vs + (cur << 12);

        // ---- S^T = K Q^T: lane holds q=ln16, keys n*16+g*4+r (raw) ----
        f32x4 sa[4] = {};
        __builtin_amdgcn_s_setprio(1);
#pragma unroll
        for (int kk = 0; kk < 2; ++kk)
#pragma unroll
            for (int n = 0; n < 4; ++n)
                sa[n] = mfma16(*(const bf16x8*)(Kr + qvOff[kk][n]), aq[kk], sa[n]);
        __builtin_amdgcn_s_setprio(0);

        float sv[4][4];
        const bool diag = CAUSAL && (kt == qt);
#pragma unroll
        for (int n = 0; n < 4; ++n)
#pragma unroll
            for (int r = 0; r < 4; ++r) {
                float s = sa[n][r];
                if (diag && (n * 16 + g * 4 + r > wave * 16 + ln16)) s = -1e30f;
                sv[n][r] = s;
            }

        // ---- row max: max3-fusable chain (8 ops) + cross-g (2 shuffles) ----
        float rm = fmaxf(fmaxf(sv[0][0], sv[0][1]), sv[0][2]);
        rm = fmaxf(fmaxf(rm, sv[0][3]), sv[1][0]);
        rm = fmaxf(fmaxf(rm, sv[1][1]), sv[1][2]);
        rm = fmaxf(fmaxf(rm, sv[1][3]), sv[2][0]);
        rm = fmaxf(fmaxf(rm, sv[2][1]), sv[2][2]);
        rm = fmaxf(fmaxf(rm, sv[2][3]), sv[3][0]);
        rm = fmaxf(fmaxf(rm, sv[3][1]), sv[3][2]);
        rm = fmaxf(rm, sv[3][3]);
        rm = fmaxf(rm, __shfl_xor(rm, 16, 64));
        rm = fmaxf(rm, __shfl_xor(rm, 32, 64));

        // ---- defer-max (T13): only rescale when max grew past headroom ----
        if (!__all(rm <= m_raw + thrRaw)) {
            const float mnew = fmaxf(m_raw, rm);
            const float al = __builtin_amdgcn_exp2f((m_raw - mnew) * sc2);
            m_raw = mnew;
            l_sum *= al;
            float alr[4];
#pragma unroll
            for (int r = 0; r < 4; ++r)
                alr[r] = __shfl(al, g * 4 + r, 64);
#pragma unroll
            for (int n = 0; n < 4; ++n)
#pragma unroll
                for (int r = 0; r < 4; ++r)
                    oa[n][r] *= alr[r];
        }
        const float nm = -m_raw * sc2;

        float rs = 0.f;
#pragma unroll
        for (int n = 0; n < 4; ++n)
#pragma unroll
            for (int r = 0; r < 4; ++r) {
                float p = __builtin_amdgcn_exp2f(fmaf(sv[n][r], sc2, nm));
                sv[n][r] = p;
                rs += p;
            }
        rs += __shfl_xor(rs, 16, 64);
        rs += __shfl_xor(rs, 32, 64);
        l_sum += rs;

        // ---- P -> LDS: 4x b64, bank-clean swizzle (hoisted offsets) ----
#pragma unroll
        for (int n = 0; n < 4; ++n) {
            uint2 w;
            w.x = pk2(sv[n][0], sv[n][1]);
            w.y = pk2(sv[n][2], sv[n][3]);
            *(uint2*)(myP + pWr[n]) = w;
        }
        asm volatile("s_waitcnt lgkmcnt(0)" ::: "memory");

        // ---- O += P @ V ----
        __builtin_amdgcn_s_setprio(1);
#pragma unroll
        for (int kk = 0; kk < 2; ++kk) {
            union { bf16x8 v; uint2 u2[2]; } pu;
            pu.u2[0] = *(const uint2*)(myP + paOff[kk] + x0);
            pu.u2[1] = *(const uint2*)(myP + paOff[kk] + (x0 ^ 4));
            bf16x8 pa = pu.v;
#pragma unroll
            for (int n = 0; n < 4; ++n)
                oa[n] = mfma16(pa, *(const bf16x8*)(Vr + qvOff[kk][n]), oa[n]);
        }
        __builtin_amdgcn_s_setprio(0);
        __syncthreads();
        cur ^= 1;
    }

    const float inv = 1.f / l_sum;
    float invr[4];
#pragma unroll
    for (int r = 0; r < 4; ++r)
        invr[r] = __shfl(inv, g * 4 + r, 64);
#pragma unroll
    for (int n = 0; n < 4; ++n)
#pragma unroll
        for (int r = 0; r < 4; ++r) {
            int q = q0 + wave * 16 + g * 4 + r;
            int d = h * 64 + n * 16 + ln16;
            O[(size_t)(b * Sq + q) * ldo + d] = f2b(oa[n][r] * invr[r]);
        }
}

// ---------------------------------------------------------------------------
// y = LN(x + a) * g + b   (D=1024, one block/row, fp32), opt bf16 copy out
// ---------------------------------------------------------------------------
template<int WRITE_BF16>
__global__ __launch_bounds__(256)
void add_ln_kernel(const float* __restrict__ X, const float* __restrict__ A,
                   const float* __restrict__ G, const float* __restrict__ Bb,
                   float* __restrict__ Y, bf16s* __restrict__ Yb)
{
    const int row = blockIdx.x, t = threadIdx.x;
    const int lane = t & 63, w = t >> 6;
    const size_t base = (size_t)row * 1024 + t * 4;
    const float4 xv = *(const float4*)(X + base);
    const float4 av = *(const float4*)(A + base);
    float4 v;
    v.x = xv.x + av.x; v.y = xv.y + av.y; v.z = xv.z + av.z; v.w = xv.w + av.w;
    float s = v.x + v.y + v.z + v.w;
    float q = v.x * v.x + v.y * v.y + v.z * v.z + v.w * v.w;
#pragma unroll
    for (int x = 1; x < 64; x <<= 1) {
        s += __shfl_xor(s, x, 64);
        q += __shfl_xor(q, x, 64);
    }
    __shared__ float red[8];
    if (lane == 0) { red[w] = s; red[4 + w] = q; }
    __syncthreads();
    s = red[0] + red[1] + red[2] + red[3];
    q = red[4] + red[5] + red[6] + red[7];
    const float mu = s * (1.f / 1024.f);
    const float var = q * (1.f / 1024.f) - mu * mu;
    const float rstd = rsqrtf(var + 1e-5f);
    const float4 gv = *(const float4*)(G + t * 4);
    const float4 bv = *(const float4*)(Bb + t * 4);
    float o0 = (v.x - mu) * rstd * gv.x + bv.x;
    float o1 = (v.y - mu) * rstd * gv.y + bv.y;
    float o2 = (v.z - mu) * rstd * gv.z + bv.z;
    float o3 = (v.w - mu) * rstd * gv.w + bv.w;
    float4 ov; ov.x = o0; ov.y = o1; ov.z = o2; ov.w = o3;
    *(float4*)(Y + base) = ov;
    if (WRITE_BF16) {
        short4 yb;
        yb.x = f2b(o0); yb.y = f2b(o1); yb.z = f2b(o2); yb.w = f2b(o3);
        *(short4*)(Yb + base) = yb;
    }
}

// ---------------------------------------------------------------------------
// launch
// ---------------------------------------------------------------------------
extern "C" void kernel_launch(void* const* d_in, const int* in_sizes, int n_in,
                              void* d_out, int out_size, void* d_ws, size_t ws_size,
                              hipStream_t stream)
{
    constexpr int Dm = 1024, DFF = 4096, Bq = 2, S = 2048;
    constexpr int NT = Bq * S;   // 4096 tokens
    constexpr size_t MM = (size_t)Dm * Dm;

    const float* x    = (const float*)d_in[0];
    const float* enc  = (const float*)d_in[1];
    const float* s_wq = (const float*)d_in[4];  const float* s_bq = (const float*)d_in[5];
    const float* s_wk = (const float*)d_in[6];  const float* s_bk = (const float*)d_in[7];
    const float* s_wv = (const float*)d_in[8];  const float* s_bv = (const float*)d_in[9];
    const float* s_wo = (const float*)d_in[10]; const float* s_bo = (const float*)d_in[11];
    const float* c_wq = (const float*)d_in[12]; const float* c_bq = (const float*)d_in[13];
    const float* c_wk = (const float*)d_in[14]; const float* c_bk = (const float*)d_in[15];
    const float* c_wv = (const float*)d_in[16]; const float* c_bv = (const float*)d_in[17];
    const float* c_wo = (const float*)d_in[18]; const float* c_bo = (const float*)d_in[19];
    const float* ffw1 = (const float*)d_in[20]; const float* ffb1 = (const float*)d_in[21];
    const float* ffw2 = (const float*)d_in[22]; const float* ffb2 = (const float*)d_in[23];
    const float* ln1g = (const float*)d_in[24]; const float* ln1b = (const float*)d_in[25];
    const float* ln2g = (const float*)d_in[26]; const float* ln2b = (const float*)d_in[27];
    const float* ln3g = (const float*)d_in[28]; const float* ln3b = (const float*)d_in[29];

    char* ws = (char*)d_ws;
    size_t off = 0;
    auto alloc = [&](size_t bytes) -> char* {
        char* p = ws + off;
        off += (bytes + 255) & ~(size_t)255;
        return p;
    };

    bf16s* xbf   = (bf16s*)alloc((size_t)NT * Dm * 2);
    bf16s* encbf = (bf16s*)alloc((size_t)NT * Dm * 2);   // contiguous with xbf
    bf16s* wAll  = (bf16s*)alloc(8 * MM * 2);            // 8 transposed 1024^2 weights
    bf16s* w1T   = (bf16s*)alloc((size_t)Dm * DFF * 2);
    bf16s* w2T   = (bf16s*)alloc((size_t)Dm * DFF * 2);
    float* bqkv  = (float*)alloc((size_t)3 * Dm * 4);
    float* bkvc  = (float*)alloc((size_t)2 * Dm * 4);
    bf16s* QKV   = (bf16s*)alloc((size_t)NT * 3 * Dm * 2);  // reused: Q2 + KV2
    bf16s* Vt    = (bf16s*)alloc((size_t)NT * Dm * 2);      // reused: V2t
    bf16s* AO    = (bf16s*)alloc((size_t)NT * Dm * 2);      // reused: AO2
    float* Pbuf  = (float*)alloc((size_t)NT * Dm * 4);      // reused: P1/P2/F
    float* x1f   = (float*)alloc((size_t)NT * Dm * 4);
    bf16s* x1bf  = (bf16s*)alloc((size_t)NT * Dm * 2);
    float* x2f   = (float*)alloc((size_t)NT * Dm * 4);
    bf16s* x2bf  = (bf16s*)alloc((size_t)NT * Dm * 2);
    bf16s* Hbuf  = (bf16s*)alloc((size_t)NT * DFF * 2);
    (void)ws_size; (void)in_sizes; (void)n_in; (void)out_size;

    bf16s* wqkvT = wAll;            // slots 0,1,2: s_wq, s_wk, s_wv
    bf16s* woTs  = wAll + 3 * MM;   // slot 3
    bf16s* wqTc  = wAll + 4 * MM;   // slot 4
    bf16s* wkvTc = wAll + 5 * MM;   // slots 5,6: c_wk, c_wv
    bf16s* woTc  = wAll + 7 * MM;   // slot 7

    // ---- phase 0: casts / transposes / bias concat ----
    cast2_f32_bf16_kernel<<<2 * NT * Dm / 8 / 256, 256, 0, stream>>>(
        x, enc, xbf, NT * Dm);
    P8 srcs = {{s_wq, s_wk, s_wv, s_wo, c_wq, c_wk, c_wv, c_wo}};
    transpose_cast8_kernel<<<dim3(16, 16, 8), 256, 0, stream>>>(srcs, wAll);
    transpose_cast_kernel<<<dim3(64, 16), 256, 0, stream>>>(ffw1, w1T, Dm, DFF);
    transpose_cast_kernel<<<dim3(16, 64), 256, 0, stream>>>(ffw2, w2T, DFF, Dm);
    concat3_kernel<<<4, 256, 0, stream>>>(s_bq, s_bk, s_bv, bqkv, Dm);
    concat2_kernel<<<4, 256, 0, stream>>>(c_bk, c_bv, bkvc, Dm);

    // ---- phase 1: self-attention ----
    gemm_bt_kernel<128, 64, 1, 0><<<dim3(24, 32), 256, 0, stream>>>(
        xbf, wqkvT, bqkv, QKV, NT, 3 * Dm, Dm);
    transpose_v_kernel<<<dim3(32, 32), 256, 0, stream>>>(
        QKV + 2 * Dm, 3 * Dm, Vt, S);
    flash_kernel<1><<<dim3(1024), 256, 0, stream>>>(
        QKV, 3 * Dm, QKV + Dm, 3 * Dm, Vt, AO, Dm, S, S, 0.125f);
    gemm_bt_kernel<64, 32, 0, 0><<<dim3(8, 64), 256, 0, stream>>>(
        AO, woTs, s_bo, Pbuf, NT, Dm, Dm);
    add_ln_kernel<1><<<NT, 256, 0, stream>>>(x, Pbuf, ln1g, ln1b, x1f, x1bf);

    // ---- phase 2: cross-attention ----
    bf16s* Q2  = QKV;
    bf16s* KV2 = QKV + (size_t)NT * Dm;
    gemm_bt_kernel<64, 32, 1, 0><<<dim3(8, 64), 256, 0, stream>>>(
        x1bf, wqTc, c_bq, Q2, NT, Dm, Dm);
    gemm_bt_kernel<128, 64, 1, 0><<<dim3(16, 32), 256, 0, stream>>>(
        encbf, wkvTc, bkvc, KV2, NT, 2 * Dm, Dm);
    transpose_v_kernel<<<dim3(32, 32), 256, 0, stream>>>(
        KV2 + Dm, 2 * Dm, Vt, S);
    flash_kernel<0><<<dim3(1024), 256, 0, stream>>>(
        Q2, Dm, KV2, 2 * Dm, Vt, AO, Dm, S, S, 0.125f);
    gemm_bt_kernel<64, 32, 0, 0><<<dim3(8, 64), 256, 0, stream>>>(
        AO, woTc, c_bo, Pbuf, NT, Dm, Dm);
    add_ln_kernel<1><<<NT, 256, 0, stream>>>(x1f, Pbuf, ln2g, ln2b, x2f, x2bf);

    // ---- phase 3: FFN ----
    gemm_bt_kernel<128, 64, 1, 1><<<dim3(32, 32), 256, 0, stream>>>(
        x2bf, w1T, ffb1, Hbuf, NT, DFF, Dm);
    gemm_bt_kernel<64, 32, 0, 0><<<dim3(8, 64), 256, 0, stream>>>(
        Hbuf, w2T, ffb2, Pbuf, NT, Dm, DFF);
    add_ln_kernel<0><<<NT, 256, 0, stream>>>(
        x2f, Pbuf, ln3g, ln3b, (float*)d_out, nullptr);
}